// Round 9
// baseline (200.930 us; speedup 1.0000x reference)
//
#include <hip/hip_runtime.h>
#include <hip/hip_bf16.h>

#define Bb 32
#define Ss 2048
#define Kk 1024   // 2*EH = 2*DH
#define Aa 512

#define BM 64                 // rows per block
#define BK 32                 // K per step
#define NT (Kk / BK)          // 32 K-tiles
#define ABUF (BM * BK * 4)    // 8 KB fp32 per A buffer

typedef __bf16 bf16x8 __attribute__((ext_vector_type(8)));
typedef float f32x4 __attribute__((ext_vector_type(4)));
typedef float f32x8 __attribute__((ext_vector_type(8)));

__device__ __forceinline__ unsigned short f2bf(float f) {
  unsigned u = __float_as_uint(f);
  u += 0x7FFFu + ((u >> 16) & 1u);   // RNE
  return (unsigned short)(u >> 16);
}

__device__ __forceinline__ float tanh_fast(float x) {
  float e = __expf(2.f * x);
  return (e - 1.f) / (e + 1.f);
}

__device__ __forceinline__ void gll16(const void* g, void* l) {
  __builtin_amdgcn_global_load_lds(
      (const __attribute__((address_space(1))) unsigned int*)g,
      (__attribute__((address_space(3))) unsigned int*)l, 16, 0, 0);
}

// ---- prep: WtT[t][g][a] = 16B chunk of bf16 W[t*32+g*8+j][a], j=0..7 ----
__global__ __launch_bounds__(256) void prep_wt(const float* __restrict__ W,
                                               unsigned short* __restrict__ WtT) {
  const int idx = blockIdx.x * 256 + threadIdx.x;   // 65536
  const int a = idx & 511;
  const int o = idx >> 9;            // octet 0..127
  const int t = o >> 2, g = o & 3;
  const int k0 = o * 8;
  unsigned short u[8];
#pragma unroll
  for (int j = 0; j < 8; ++j) u[j] = f2bf(W[(size_t)(k0 + j) * Aa + a]);
  uint4 pk;
  pk.x = (unsigned)u[0] | ((unsigned)u[1] << 16);
  pk.y = (unsigned)u[2] | ((unsigned)u[3] << 16);
  pk.z = (unsigned)u[4] | ((unsigned)u[5] << 16);
  pk.w = (unsigned)u[6] | ((unsigned)u[7] << 16);
  *(uint4*)((char*)WtT + (size_t)t * 32768 + g * 8192 + a * 16) = pk;
}

// ---- temp2 = [dh0|dh1] @ U ----
__global__ __launch_bounds__(256) void t2_partial(const float* __restrict__ dh,
                                                  const float* __restrict__ U,
                                                  float* __restrict__ part) {
  const int b = blockIdx.x, kc = blockIdx.y, t = threadIdx.x;  // (32, 8)
  __shared__ float sdh[128];
  if (t < 128) {
    int k = kc * 128 + t;
    sdh[t] = dh[(k >> 9) * (Bb * 512) + b * 512 + (k & 511)];
  }
  __syncthreads();
#pragma unroll
  for (int h = 0; h < 2; ++h) {
    const int a = h * 256 + t;
    float s = 0.f;
#pragma unroll 8
    for (int kk = 0; kk < 128; ++kk) s += sdh[kk] * U[(size_t)(kc * 128 + kk) * Aa + a];
    part[(size_t)(b * 8 + kc) * Aa + a] = s;
  }
}

__global__ __launch_bounds__(256) void t2_reduce(const float* __restrict__ part,
                                                 float* __restrict__ t2) {
  const int idx = blockIdx.x * 256 + threadIdx.x;  // 16384
  const int b = idx >> 9, a = idx & 511;
  float s = 0.f;
#pragma unroll
  for (int kc = 0; kc < 8; ++kc) s += part[(size_t)(b * 8 + kc) * Aa + a];
  t2[idx] = s;
}

// ---- main: scores = tanh(enc@W + t2) @ v ----
// Block 256 thr (4 waves), tile 64x512. A: gll fp32 -> 3 LDS bufs (24 KB),
// source-XOR swizzle, 2 iters ahead. B: per-wave global->VGPR dwordx4 from
// WtT image, 2 reg sets, loaded post-MFMA. One vmcnt(10) + one barrier/iter.

#define VM(N)                                                                   \
  asm volatile("s_waitcnt vmcnt(" #N ")" ::: "memory");                         \
  __builtin_amdgcn_sched_barrier(0);

// issue A-tile TT into LDS buffer DST (2 glls/thread, source-XOR within row)
#define AGLL(DST, TT)                                                           \
  if ((TT) < NT) {                                                              \
    const char* eb_ = encC + (TT) * 128;                                        \
    gll16(eb_ + a_gs0, (DST) + a_ld0);                                          \
    gll16(eb_ + a_gs1, (DST) + a_ld1);                                          \
  }

// load B-tile TT into register set BS (8 dwordx4/lane)
#define BLOAD(BS, TT)                                                           \
  if ((TT) < NT) {                                                              \
    const char* wb_ = wtB + (size_t)(TT) * 32768 + b_voff;                      \
    _Pragma("unroll")                                                           \
    for (int ni = 0; ni < 8; ++ni)                                              \
      BS[ni] = *(const bf16x8*)(wb_ + ni * 256);                                \
  }

// one K-step
#define ITER(AC, BC, AN2, T, VMN)                                               \
  {                                                                             \
    AGLL(AN2, (T) + 2)                                                          \
    __builtin_amdgcn_sched_barrier(0);  /* keep gll before B-loads in FIFO */   \
    bf16x8 af[4];                                                               \
    _Pragma("unroll")                                                           \
    for (int mi = 0; mi < 4; ++mi) {                                            \
      const int rr = mi * 16 + (lane & 15);                                     \
      const int s0 = (lane >> 4) * 2;                                           \
      f32x4 lo = *(const f32x4*)((AC) + rr * 128 + (((s0) ^ (rr & 7)) << 4));   \
      f32x4 hi = *(const f32x4*)((AC) + rr * 128 + (((s0 + 1) ^ (rr & 7)) << 4)); \
      f32x8 w8 = {lo.x, lo.y, lo.z, lo.w, hi.x, hi.y, hi.z, hi.w};              \
      af[mi] = __builtin_convertvector(w8, bf16x8);                             \
    }                                                                           \
    __builtin_amdgcn_s_setprio(1);                                              \
    _Pragma("unroll")                                                           \
    for (int mi = 0; mi < 4; ++mi)                                              \
      _Pragma("unroll")                                                         \
      for (int ni = 0; ni < 8; ++ni)                                            \
        acc[mi][ni] = __builtin_amdgcn_mfma_f32_16x16x32_bf16(af[mi], BC[ni], acc[mi][ni], 0, 0, 0); \
    __builtin_amdgcn_s_setprio(0);                                              \
    BLOAD(BC, (T) + 2)                                                          \
    VM(VMN);                                                                    \
    __builtin_amdgcn_s_barrier();                                               \
  }

__global__ __launch_bounds__(256) void score_gemm(const float* __restrict__ enc,
                                                  const unsigned short* __restrict__ WtT,
                                                  const float* __restrict__ t2,
                                                  const float* __restrict__ v,
                                                  float* __restrict__ score) {
  __shared__ __align__(16) char lds[3 * ABUF];   // 24 KB
  char* sA0 = lds;
  char* sA1 = lds + ABUF;
  char* sA2 = lds + 2 * ABUF;

  const int blk = blockIdx.x;               // 1024 blocks
  const int b = blk >> 5, sc = blk & 31;
  const char* encC = (const char*)(enc + (size_t)(b * Ss + sc * BM) * Kk);
  const char* wtB = (const char*)WtT;

  const int tid = threadIdx.x;
  const int lane = tid & 63;
  const int wx = tid >> 6;                  // 4 waves, wave tile 64x128

  // A gll: chunk c (512 of 16B): row = c>>3, kc = c&7; source kc' = kc^(row&7)
  const int a_c0 = tid, a_c1 = 256 + tid;
  const int a_r0 = a_c0 >> 3, a_r1 = a_c1 >> 3;
  const int a_gs0 = a_r0 * 4096 + ((a_c0 & 7) ^ (a_r0 & 7)) * 16;
  const int a_gs1 = a_r1 * 4096 + ((a_c1 & 7) ^ (a_r1 & 7)) * 16;
  const int a_ld0 = a_c0 * 16;
  const int a_ld1 = a_c1 * 16;

  // B per-lane offset within a K-tile image: [g=lane>>4][col]*16
  const int b_voff = (lane >> 4) * 8192 + wx * 2048 + (lane & 15) * 16;

  const f32x4 zero = {0.f, 0.f, 0.f, 0.f};
  f32x4 acc[4][8];
#pragma unroll
  for (int i = 0; i < 4; ++i)
#pragma unroll
    for (int j = 0; j < 8; ++j) acc[i][j] = zero;

  bf16x8 b0[8], b1[8];

  // ---- prologue: FIFO [gll0:2, B0:8, gll1:2, B1:8]; vmcnt(10) retires 0s ----
  {
    AGLL(sA0, 0)
    __builtin_amdgcn_sched_barrier(0);
    BLOAD(b0, 0)
    __builtin_amdgcn_sched_barrier(0);
    AGLL(sA1, 1)
    __builtin_amdgcn_sched_barrier(0);
    BLOAD(b1, 1)
    VM(10);
    __builtin_amdgcn_s_barrier();
  }

  // steady: t = 0..29, bufs period 6 (A mod 3, B mod 2)
  for (int t = 0; t < 30; t += 6) {
    ITER(sA0, b0, sA2, t + 0, 10)
    ITER(sA1, b1, sA0, t + 1, 10)
    ITER(sA2, b0, sA1, t + 2, 10)
    ITER(sA0, b1, sA2, t + 3, 10)
    ITER(sA1, b0, sA0, t + 4, 10)
    ITER(sA2, b1, sA1, t + 5, 10)
  }
  // tail: t=30 (no issues; drain), t=31
  ITER(sA0, b0, sA2, 30, 0)
  ITER(sA1, b1, sA0, 31, 0)

  // ---- epilogue: score_row += tanh(acc + t2[col]) * v[col] ----
  float t2v[8], vv[8];
#pragma unroll
  for (int ni = 0; ni < 8; ++ni) {
    int c = wx * 128 + ni * 16 + (lane & 15);
    t2v[ni] = t2[b * Aa + c];
    vv[ni] = v[c];
  }
  float sp[4][4];
#pragma unroll
  for (int mi = 0; mi < 4; ++mi)
#pragma unroll
    for (int j = 0; j < 4; ++j) sp[mi][j] = 0.f;
#pragma unroll
  for (int mi = 0; mi < 4; ++mi)
#pragma unroll
    for (int ni = 0; ni < 8; ++ni)
#pragma unroll
      for (int j = 0; j < 4; ++j) {
        float x = acc[mi][ni][j] + t2v[ni];
        sp[mi][j] += vv[ni] * tanh_fast(x);
      }

  // C/D layout: col = lane&15, row = mi*16 + (lane>>4)*4 + j.
  float* sbuf = (float*)lds;   // 1 KB, disjoint from last-read A buf regions
#pragma unroll
  for (int mi = 0; mi < 4; ++mi)
#pragma unroll
    for (int j = 0; j < 4; ++j) {
      float s = sp[mi][j];
      s += __shfl_xor(s, 1);
      s += __shfl_xor(s, 2);
      s += __shfl_xor(s, 4);
      s += __shfl_xor(s, 8);
      if ((lane & 15) == 0) {
        int r = mi * 16 + ((lane >> 4) << 2) + j;
        sbuf[r * 4 + wx] = s;
      }
    }
  __syncthreads();
  if (tid < BM) {
    float s = sbuf[tid * 4] + sbuf[tid * 4 + 1] + sbuf[tid * 4 + 2] + sbuf[tid * 4 + 3];
    score[b * Ss + sc * BM + tid] = s;
  }
}

// ---- softmax over S, in place in d_out's attention region ----
__global__ __launch_bounds__(256) void softmax_k(float* __restrict__ aw) {
  const int b = blockIdx.x, t = threadIdx.x;
  __shared__ float red[8];
  float s[8];
  float m = -3.4e38f;
#pragma unroll
  for (int i = 0; i < 8; ++i) {
    s[i] = aw[b * Ss + t + i * 256];
    m = fmaxf(m, s[i]);
  }
#pragma unroll
  for (int off = 1; off < 64; off <<= 1) m = fmaxf(m, __shfl_xor(m, off));
  const int lane = t & 63, wv = t >> 6;
  if (lane == 0) red[wv] = m;
  __syncthreads();
  m = fmaxf(fmaxf(red[0], red[1]), fmaxf(red[2], red[3]));
  float e[8];
  float l = 0.f;
#pragma unroll
  for (int i = 0; i < 8; ++i) { e[i] = __expf(s[i] - m); l += e[i]; }
#pragma unroll
  for (int off = 1; off < 64; off <<= 1) l += __shfl_xor(l, off);
  if (lane == 0) red[4 + wv] = l;
  __syncthreads();
  l = red[4] + red[5] + red[6] + red[7];
  const float inv = 1.f / l;
#pragma unroll
  for (int i = 0; i < 8; ++i) aw[b * Ss + t + i * 256] = e[i] * inv;
}

// ---- context = sum_s aw[s] * enc[b,s,:] ----
__global__ __launch_bounds__(256) void ctx_partial(const float* __restrict__ enc,
                                                   const float* __restrict__ aw,
                                                   float* __restrict__ part) {
  const int b = blockIdx.x, ch = blockIdx.y, t = threadIdx.x;  // (32, 32)
  __shared__ float sw[64];
  const int s0 = ch * 64;
  if (t < 64) sw[t] = aw[b * Ss + s0 + t];
  __syncthreads();
  float ax = 0.f, ay = 0.f, az = 0.f, aww = 0.f;
  const float* ebase = enc + (size_t)(b * Ss + s0) * Kk + t * 4;
#pragma unroll 4
  for (int r = 0; r < 64; ++r) {
    const float4 ev = *(const float4*)(ebase + (size_t)r * Kk);
    const float w = sw[r];
    ax += w * ev.x; ay += w * ev.y; az += w * ev.z; aww += w * ev.w;
  }
  float4 o; o.x = ax; o.y = ay; o.z = az; o.w = aww;
  *(float4*)(part + (size_t)(b * 32 + ch) * Kk + t * 4) = o;
}

__global__ __launch_bounds__(256) void ctx_reduce(const float* __restrict__ part,
                                                  float* __restrict__ ctx) {
  const int idx = blockIdx.x * 256 + threadIdx.x;   // 32768
  const int b = idx >> 10, e = idx & 1023;
  float s = 0.f;
#pragma unroll
  for (int ch = 0; ch < 32; ++ch) s += part[(size_t)(b * 32 + ch) * Kk + e];
  ctx[idx] = s;
}

extern "C" void kernel_launch(void* const* d_in, const int* in_sizes, int n_in,
                              void* d_out, int out_size, void* d_ws, size_t ws_size,
                              hipStream_t stream) {
  const float* dh  = (const float*)d_in[0];   // (2, 32, 512)
  const float* enc = (const float*)d_in[1];   // (32, 2048, 1024)
  const float* W   = (const float*)d_in[2];   // (1024, 512)
  const float* U   = (const float*)d_in[3];   // (1024, 512)
  const float* v   = (const float*)d_in[4];   // (512, 1)

  float* out_ctx = (float*)d_out;             // (32, 1, 1024) = 32768
  float* out_aw  = (float*)d_out + 32768;     // (32, 2048)    = 65536

  char* ws = (char*)d_ws;
  unsigned short* WtT = (unsigned short*)ws;                // 1 MB (octet-major)
  float* t2p   = (float*)(ws + 1048576);                    // 512 KB
  float* t2    = (float*)(ws + 1048576 + 524288);           // 64 KB
  float* cpart = (float*)(ws + 1048576 + 524288 + 65536);   // 4 MB

  prep_wt<<<256, 256, 0, stream>>>(W, WtT);
  t2_partial<<<dim3(32, 8), 256, 0, stream>>>(dh, U, t2p);
  t2_reduce<<<64, 256, 0, stream>>>(t2p, t2);
  score_gemm<<<1024, 256, 0, stream>>>(enc, WtT, t2, v, out_aw);
  softmax_k<<<32, 256, 0, stream>>>(out_aw);
  ctx_partial<<<dim3(32, 32), 256, 0, stream>>>(enc, out_aw, cpart);
  ctx_reduce<<<128, 256, 0, stream>>>(cpart, out_ctx);
}

// Round 11
// 179.806 us; speedup vs baseline: 1.1175x; 1.1175x over previous
//
#include <hip/hip_runtime.h>
#include <hip/hip_bf16.h>

#define Bb 32
#define Ss 2048
#define Kk 1024   // 2*EH = 2*DH
#define Aa 512

#define BM 64                 // rows per block
#define BN 256                // A-cols per block (slice)
#define BK 32                 // K per step
#define NT (Kk / BK)          // 32 K-tiles
#define ABUF (BM * BK * 2)    // 4 KB bf16  [q4][row64] 16B chunks
#define BBUF (BN * BK * 2)    // 16 KB bf16 [q4][col256] 16B chunks

typedef __bf16 bf16x8 __attribute__((ext_vector_type(8)));
typedef float f32x4 __attribute__((ext_vector_type(4)));
typedef float f32x8 __attribute__((ext_vector_type(8)));

__device__ __forceinline__ unsigned short f2bf(float f) {
  unsigned u = __float_as_uint(f);
  u += 0x7FFFu + ((u >> 16) & 1u);   // RNE
  return (unsigned short)(u >> 16);
}

__device__ __forceinline__ float tanh_fast(float x) {
  float e = __expf(2.f * x);
  return (e - 1.f) / (e + 1.f);
}

__device__ __forceinline__ void gll16(const void* g, void* l) {
  __builtin_amdgcn_global_load_lds(
      (const __attribute__((address_space(1))) unsigned int*)g,
      (__attribute__((address_space(3))) unsigned int*)l, 16, 0, 0);
}

// ---- prep: WtT tile image, per (t, slice): [q4][col256] 16B chunks of
// bf16 W[t*32+q*8+j][slice*256+col], j=0..7. 64 images x 16 KB = 1 MB. ----
__global__ __launch_bounds__(256) void prep_wt(const float* __restrict__ W,
                                               unsigned short* __restrict__ WtT) {
  const int idx = blockIdx.x * 256 + threadIdx.x;   // 65536 chunks
  const int col = idx & 255;
  const int q = (idx >> 8) & 3;
  const int sl = (idx >> 10) & 1;
  const int t = idx >> 11;
  const int k0 = t * 32 + q * 8;
  const int a = sl * 256 + col;
  unsigned short u[8];
#pragma unroll
  for (int j = 0; j < 8; ++j) u[j] = f2bf(W[(size_t)(k0 + j) * Aa + a]);
  uint4 pk;
  pk.x = (unsigned)u[0] | ((unsigned)u[1] << 16);
  pk.y = (unsigned)u[2] | ((unsigned)u[3] << 16);
  pk.z = (unsigned)u[4] | ((unsigned)u[5] << 16);
  pk.w = (unsigned)u[6] | ((unsigned)u[7] << 16);
  *(uint4*)((char*)WtT + (size_t)((t * 2 + sl) * 1024 + q * 256 + col) * 16) = pk;
}

// ---- temp2 = [dh0|dh1] @ U ----
__global__ __launch_bounds__(256) void t2_partial(const float* __restrict__ dh,
                                                  const float* __restrict__ U,
                                                  float* __restrict__ part) {
  const int b = blockIdx.x, kc = blockIdx.y, t = threadIdx.x;  // (32, 8)
  __shared__ float sdh[128];
  if (t < 128) {
    int k = kc * 128 + t;
    sdh[t] = dh[(k >> 9) * (Bb * 512) + b * 512 + (k & 511)];
  }
  __syncthreads();
#pragma unroll
  for (int h = 0; h < 2; ++h) {
    const int a = h * 256 + t;
    float s = 0.f;
#pragma unroll 8
    for (int kk = 0; kk < 128; ++kk) s += sdh[kk] * U[(size_t)(kc * 128 + kk) * Aa + a];
    part[(size_t)(b * 8 + kc) * Aa + a] = s;
  }
}

__global__ __launch_bounds__(256) void t2_reduce(const float* __restrict__ part,
                                                 float* __restrict__ t2) {
  const int idx = blockIdx.x * 256 + threadIdx.x;  // 16384
  const int b = idx >> 9, a = idx & 511;
  float s = 0.f;
#pragma unroll
  for (int kc = 0; kc < 8; ++kc) s += part[(size_t)(b * 8 + kc) * Aa + a];
  t2[idx] = s;
}

// ---- main: partial scores = tanh(enc@W + t2) @ v over a 256-col A slice ----
// Block 256 thr (4 waves), tile 64x256, wave 64x64, acc=64/lane (occupancy
// fix: unified VGPR+AGPR budget ~165 -> 3 waves/SIMD). A: global->reg
// (issue-early) -> bf16 -> ds_write (write-late). B: gll from WtT image
// (4 chunks/thread = exactly 16 KB). One vmcnt(6) + two barriers per iter.

#define VM(N)                                                                   \
  asm volatile("s_waitcnt vmcnt(" #N ")" ::: "memory");                         \
  __builtin_amdgcn_sched_barrier(0);

#define ALOAD(S, TT)                                                            \
  if ((TT) < NT) {                                                              \
    const float* ap_ = aG + (TT) * BK;                                          \
    areg[S][0] = *(const float4*)ap_;                                           \
    areg[S][1] = *(const float4*)(ap_ + 4);                                     \
  }

#define AWRITE(DST, S)                                                          \
  {                                                                             \
    f32x8 w8_ = {areg[S][0].x, areg[S][0].y, areg[S][0].z, areg[S][0].w,        \
                 areg[S][1].x, areg[S][1].y, areg[S][1].z, areg[S][1].w};       \
    *(bf16x8*)((DST) + a_wb) = __builtin_convertvector(w8_, bf16x8);            \
  }

#define BGLL(TT, DST)                                                           \
  if ((TT) < NT) {                                                              \
    const char* wb_ = wtB + (size_t)((TT) * 2 + slice) * 16384;                 \
    gll16(wb_ + b_c0, (DST) + b_c0);                                            \
    gll16(wb_ + b_c1, (DST) + b_c1);                                            \
    gll16(wb_ + b_c2, (DST) + b_c2);                                            \
    gll16(wb_ + b_c3, (DST) + b_c3);                                            \
  }

// Ledger (per thread, strict issue order): iter T issues A(T+2):2 then
// B(T+2):4. At the wait, outstanding = A(T+1):2, B(T+1):4, A(T+2):2,
// B(T+2):4 = 12 -> VM(6) retires exactly {A(T+1), B(T+1)}.
#define ITER(AC, BC, AN, SL, SW, T, VMN)                                        \
  {                                                                             \
    bf16x8 af[4], bfr[4];                                                       \
    _Pragma("unroll")                                                           \
    for (int mi = 0; mi < 4; ++mi)                                              \
      af[mi] = *(const bf16x8*)((AC) + (lane >> 4) * 1024 +                     \
                                (mi * 16 + (lane & 15)) * 16);                  \
    _Pragma("unroll")                                                           \
    for (int ni = 0; ni < 4; ++ni)                                              \
      bfr[ni] = *(const bf16x8*)((BC) + (lane >> 4) * 4096 +                    \
                                 (wx * 64 + ni * 16 + (lane & 15)) * 16);       \
    ALOAD(SL, (T) + 2)                                                          \
    __builtin_amdgcn_s_setprio(1);                                              \
    _Pragma("unroll")                                                           \
    for (int mi = 0; mi < 4; ++mi)                                              \
      _Pragma("unroll")                                                         \
      for (int ni = 0; ni < 4; ++ni)                                            \
        acc[mi][ni] = __builtin_amdgcn_mfma_f32_16x16x32_bf16(af[mi], bfr[ni], acc[mi][ni], 0, 0, 0); \
    __builtin_amdgcn_s_setprio(0);                                              \
    __builtin_amdgcn_sched_barrier(0);                                          \
    __builtin_amdgcn_s_barrier();   /* all waves done reading AC/BC */          \
    BGLL((T) + 2, BC)                                                           \
    VM(VMN)                                                                     \
    if ((T) + 1 < NT) { AWRITE(AN, SW) }                                        \
    asm volatile("s_waitcnt lgkmcnt(0)" ::: "memory");                          \
    __builtin_amdgcn_sched_barrier(0);                                          \
    __builtin_amdgcn_s_barrier();   /* tile T+1 published */                    \
  }

__global__ __launch_bounds__(256, 3) void score_gemm(const float* __restrict__ enc,
                                                     const unsigned short* __restrict__ WtT,
                                                     const float* __restrict__ t2,
                                                     const float* __restrict__ v,
                                                     float* __restrict__ psc) {
  __shared__ __align__(16) char lds[2 * ABUF + 2 * BBUF];   // 40 KB
  char* sA0 = lds;
  char* sA1 = lds + ABUF;
  char* sB0 = lds + 2 * ABUF;
  char* sB1 = lds + 2 * ABUF + BBUF;

  const int blk = blockIdx.x;               // 2048 blocks
  const int mtile = blk >> 1, slice = blk & 1;
  const int b = mtile >> 5;                 // batch (64-row tiles, 32/batch)
  const float* encF = enc + (size_t)mtile * BM * Kk;
  const char* wtB = (const char*)WtT;

  const int tid = threadIdx.x;
  const int lane = tid & 63;
  const int wx = tid >> 6;                  // 4 waves, wave tile 64x64

  // A stage: thread -> (row = tid>>2, q = tid&3); 32B global -> 16B bf16 LDS
  const int a_row = tid >> 2;
  const int a_q = tid & 3;
  const float* aG = encF + (size_t)a_row * Kk + a_q * 8;
  const int a_wb = a_q * 1024 + a_row * 16;

  // B gll chunk offsets: c = j*256 + tid, j=0..3 (1024 chunks = 16 KB exact)
  const int b_c0 = (0 * 256 + tid) * 16;
  const int b_c1 = (1 * 256 + tid) * 16;
  const int b_c2 = (2 * 256 + tid) * 16;
  const int b_c3 = (3 * 256 + tid) * 16;

  const f32x4 zero = {0.f, 0.f, 0.f, 0.f};
  f32x4 acc[4][4];
#pragma unroll
  for (int i = 0; i < 4; ++i)
#pragma unroll
    for (int j = 0; j < 4; ++j) acc[i][j] = zero;

  float4 areg[2][2];   // two A prefetch sets, literal indices only

  // ---- prologue: FIFO [A0:2, B0:4, A1:2, B1:4] = 12 ----
  {
    ALOAD(0, 0)
    __builtin_amdgcn_sched_barrier(0);
    BGLL(0, sB0)
    __builtin_amdgcn_sched_barrier(0);
    ALOAD(1, 1)
    __builtin_amdgcn_sched_barrier(0);
    BGLL(1, sB1)
    VM(10)                        // retire A0 regs
    AWRITE(sA0, 0)
    VM(6)                         // retire B0; leaves A1:2 + B1:4 = 6
    asm volatile("s_waitcnt lgkmcnt(0)" ::: "memory");
    __builtin_amdgcn_sched_barrier(0);
    __builtin_amdgcn_s_barrier();
  }

  for (int t = 0; t < 30; t += 2) {
    ITER(sA0, sB0, sA1, 0, 1, t, 6)
    ITER(sA1, sB1, sA0, 1, 0, t + 1, 6)
  }
  ITER(sA0, sB0, sA1, 0, 1, 30, 0)
  ITER(sA1, sB1, sA0, 1, 0, 31, 0)

  // ---- epilogue: partial score += tanh(acc + t2[c]) * v[c] over 256 cols ----
  float t2v[4], vv[4];
#pragma unroll
  for (int ni = 0; ni < 4; ++ni) {
    int c = slice * BN + wx * 64 + ni * 16 + (lane & 15);
    t2v[ni] = t2[b * Aa + c];
    vv[ni] = v[c];
  }
  float sp[4][4];
#pragma unroll
  for (int mi = 0; mi < 4; ++mi)
#pragma unroll
    for (int j = 0; j < 4; ++j) sp[mi][j] = 0.f;
#pragma unroll
  for (int mi = 0; mi < 4; ++mi)
#pragma unroll
    for (int ni = 0; ni < 4; ++ni)
#pragma unroll
      for (int j = 0; j < 4; ++j) {
        float x = acc[mi][ni][j] + t2v[ni];
        sp[mi][j] += vv[ni] * tanh_fast(x);
      }

  // C/D layout: col = lane&15, row = mi*16 + (lane>>4)*4 + j.
  float* sbuf = (float*)lds;   // 1 KB scratch
#pragma unroll
  for (int mi = 0; mi < 4; ++mi)
#pragma unroll
    for (int j = 0; j < 4; ++j) {
      float s = sp[mi][j];
      s += __shfl_xor(s, 1);
      s += __shfl_xor(s, 2);
      s += __shfl_xor(s, 4);
      s += __shfl_xor(s, 8);
      if ((lane & 15) == 0) {
        int r = mi * 16 + ((lane >> 4) << 2) + j;
        sbuf[r * 4 + wx] = s;
      }
    }
  __syncthreads();
  if (tid < BM) {
    float s = sbuf[tid * 4] + sbuf[tid * 4 + 1] + sbuf[tid * 4 + 2] + sbuf[tid * 4 + 3];
    psc[slice * 65536 + mtile * BM + tid] = s;
  }
}

// ---- softmax over S: combine the two A-slice partials, write aw ----
__global__ __launch_bounds__(256) void softmax_k(const float* __restrict__ psc,
                                                 float* __restrict__ aw) {
  const int b = blockIdx.x, t = threadIdx.x;
  __shared__ float red[8];
  float s[8];
  float m = -3.4e38f;
#pragma unroll
  for (int i = 0; i < 8; ++i) {
    int idx = b * Ss + t + i * 256;
    s[i] = psc[idx] + psc[65536 + idx];
    m = fmaxf(m, s[i]);
  }
#pragma unroll
  for (int off = 1; off < 64; off <<= 1) m = fmaxf(m, __shfl_xor(m, off));
  const int lane = t & 63, wv = t >> 6;
  if (lane == 0) red[wv] = m;
  __syncthreads();
  m = fmaxf(fmaxf(red[0], red[1]), fmaxf(red[2], red[3]));
  float e[8];
  float l = 0.f;
#pragma unroll
  for (int i = 0; i < 8; ++i) { e[i] = __expf(s[i] - m); l += e[i]; }
#pragma unroll
  for (int off = 1; off < 64; off <<= 1) l += __shfl_xor(l, off);
  if (lane == 0) red[4 + wv] = l;
  __syncthreads();
  l = red[4] + red[5] + red[6] + red[7];
  const float inv = 1.f / l;
#pragma unroll
  for (int i = 0; i < 8; ++i) aw[b * Ss + t + i * 256] = e[i] * inv;
}

// ---- context = sum_s aw[s] * enc[b,s,:] ----
__global__ __launch_bounds__(256) void ctx_partial(const float* __restrict__ enc,
                                                   const float* __restrict__ aw,
                                                   float* __restrict__ part) {
  const int b = blockIdx.x, ch = blockIdx.y, t = threadIdx.x;  // (32, 32)
  __shared__ float sw[64];
  const int s0 = ch * 64;
  if (t < 64) sw[t] = aw[b * Ss + s0 + t];
  __syncthreads();
  float ax = 0.f, ay = 0.f, az = 0.f, aww = 0.f;
  const float* ebase = enc + (size_t)(b * Ss + s0) * Kk + t * 4;
#pragma unroll 4
  for (int r = 0; r < 64; ++r) {
    const float4 ev = *(const float4*)(ebase + (size_t)r * Kk);
    const float w = sw[r];
    ax += w * ev.x; ay += w * ev.y; az += w * ev.z; aww += w * ev.w;
  }
  float4 o; o.x = ax; o.y = ay; o.z = az; o.w = aww;
  *(float4*)(part + (size_t)(b * 32 + ch) * Kk + t * 4) = o;
}

__global__ __launch_bounds__(256) void ctx_reduce(const float* __restrict__ part,
                                                  float* __restrict__ ctx) {
  const int idx = blockIdx.x * 256 + threadIdx.x;   // 32768
  const int b = idx >> 10, e = idx & 1023;
  float s = 0.f;
#pragma unroll
  for (int ch = 0; ch < 32; ++ch) s += part[(size_t)(b * 32 + ch) * Kk + e];
  ctx[idx] = s;
}

extern "C" void kernel_launch(void* const* d_in, const int* in_sizes, int n_in,
                              void* d_out, int out_size, void* d_ws, size_t ws_size,
                              hipStream_t stream) {
  const float* dh  = (const float*)d_in[0];   // (2, 32, 512)
  const float* enc = (const float*)d_in[1];   // (32, 2048, 1024)
  const float* W   = (const float*)d_in[2];   // (1024, 512)
  const float* U   = (const float*)d_in[3];   // (1024, 512)
  const float* v   = (const float*)d_in[4];   // (512, 1)

  float* out_ctx = (float*)d_out;             // (32, 1, 1024) = 32768
  float* out_aw  = (float*)d_out + 32768;     // (32, 2048)    = 65536

  char* ws = (char*)d_ws;
  unsigned short* WtT = (unsigned short*)ws;                          // 1 MB
  float* t2p   = (float*)(ws + 1048576);                              // 512 KB
  float* t2    = (float*)(ws + 1048576 + 524288);                     // 64 KB
  float* cpart = (float*)(ws + 1048576 + 524288 + 65536);             // 4 MB
  float* psc   = (float*)(ws + 1048576 + 524288 + 65536 + 4194304);   // 512 KB

  prep_wt<<<256, 256, 0, stream>>>(W, WtT);
  t2_partial<<<dim3(32, 8), 256, 0, stream>>>(dh, U, t2p);
  t2_reduce<<<64, 256, 0, stream>>>(t2p, t2);
  score_gemm<<<2048, 256, 0, stream>>>(enc, WtT, t2, v, psc);
  softmax_k<<<32, 256, 0, stream>>>(psc, out_aw);
  ctx_partial<<<dim3(32, 32), 256, 0, stream>>>(enc, out_aw, cpart);
  ctx_reduce<<<128, 256, 0, stream>>>(cpart, out_ctx);
}